// Round 15
// baseline (115.833 us; speedup 1.0000x reference)
//
#include <hip/hip_runtime.h>
#include <hip/hip_bf16.h>
#include <hip/hip_fp16.h>

#define NTOK 16384
#define HDIM 2048
#define NEXP 128
#define KSEL 8
#define NCAND 16
#define DELTA_GAP 1e-4f     // 3-product err sigma ~1e-6; np-ref err ~2.5e-5; proven R5-R14
#define LO_SCALE 2048.0f    // 2^11: keeps lo-planes in fp16 normal range
#define LO_INV (1.0f/2048.0f)

typedef _Float16 half8  __attribute__((ext_vector_type(8)));
typedef float    f32x4  __attribute__((ext_vector_type(4)));

// ===========================================================================
// Kernel 0: W fp32 -> fragment-major fp16 hi/lo planes (once, 1 MB, L2-hot).
// Fragment (ks, eg): halfword index ((ks*8 + eg)*64 + l)*8 + j holds
// w[16*eg + (l&15)][32*ks + 8*(l>>4) + j]  (layout proven rounds 4-14).
// ===========================================================================
__global__ __launch_bounds__(256) void w_convert(
    const float* __restrict__ w, _Float16* __restrict__ whp, _Float16* __restrict__ wlp)
{
    const int e = blockIdx.x;            // 0..127
    const int k = threadIdx.x * 8;       // 0..2040
    const float* src = w + (size_t)e * HDIM + k;
    const f32x4 v0 = *reinterpret_cast<const f32x4*>(src);
    const f32x4 v1 = *reinterpret_cast<const f32x4*>(src + 4);
    float vv[8] = {v0[0], v0[1], v0[2], v0[3], v1[0], v1[1], v1[2], v1[3]};
    half8 h, lo;
#pragma unroll
    for (int j = 0; j < 8; ++j) {
        const _Float16 hj = (_Float16)vv[j];
        h[j]  = hj;
        lo[j] = (_Float16)((vv[j] - (float)hj) * LO_SCALE);
    }
    const int ks = k >> 5;
    const int eg = e >> 4;
    const int l  = (e & 15) | (((k >> 3) & 3) << 4);
    const size_t di = ((size_t)(ks * 8 + eg) * 64 + l) * 8;
    *reinterpret_cast<half8*>(whp + di) = h;
    *reinterpret_cast<half8*>(wlp + di) = lo;
}

// ===========================================================================
// Kernel 1: split-fp16 3-product MFMA GEMM, EXPERT-SPLIT for low registers.
// Grid 512 x 256 thr = 4 waves; wave = 32 tokens x 64 EXPERTS (eh half) x
// one K-half (1024 k = 32 steps of 32). acc+acc2 = 64 regs (vs 128 in
// R12/R14 — that 128 + 128-VGPR arch cap is what serialized all loads).
// Total ~160 regs -> launch_bounds(256,3): 12 waves/CU TLP (R11 regime).
// Per step: 8 B-loads (direct from fragment-major planes, L1/L2-hot) +
// 4 A-loads + 24 MFMA. No LDS / barriers in K-loop. Epilogue: 32KB LDS
// exchange [kh][eh], sum over kh, concat eh, then proven R12 epilogue.
// ===========================================================================
__global__ __launch_bounds__(256, 3) void gemm3_split(
    const float* __restrict__ x,
    const _Float16* __restrict__ whp, const _Float16* __restrict__ wlp,
    float* __restrict__ logits, float* __restrict__ topv, float* __restrict__ topi,
    int* __restrict__ cand, int* __restrict__ flag)
{
    __shared__ f32x4 red[2][2][2][4][64];   // [kh][eh][ms][g][lane] = 32 KB

    const int tid = threadIdx.x;
    const int l   = tid & 63;
    const int W   = tid >> 6;        // wave 0..3
    const int eh  = W & 1;           // expert half: eg = 4*eh + g
    const int kh  = W >> 1;          // K half: k in [kh*1024, kh*1024+1024)
    const int t0  = blockIdx.x * 32;

    // A: lane covers rows t0+(l&15) / +16, k-octet 8*(l>>4) per 32-k step
    const float* xrow0 = x + (size_t)(t0 + (l & 15)) * HDIM + kh * 1024 + 8 * (l >> 4);
    const float* xrow1 = xrow0 + (size_t)16 * HDIM;

    f32x4 acc[2][4], acc2[2][4];
#pragma unroll
    for (int ms = 0; ms < 2; ++ms)
#pragma unroll
        for (int g = 0; g < 4; ++g) {
            acc[ms][g]  = (f32x4){0.f, 0.f, 0.f, 0.f};
            acc2[ms][g] = (f32x4){0.f, 0.f, 0.f, 0.f};
        }

#pragma unroll 1
    for (int s = 0; s < 32; ++s) {
        const int ks = kh * 32 + s;

        // B(s): 8 coalesced 16B/lane loads (same addrs across all blocks)
        half8 bh[4], bl[4];
#pragma unroll
        for (int g = 0; g < 4; ++g) {
            const size_t off = (size_t)(ks * 8 + 4 * eh + g) * 512 + l * 8;
            bh[g] = *reinterpret_cast<const half8*>(whp + off);
            bl[g] = *reinterpret_cast<const half8*>(wlp + off);
        }

        // A(s): 4 loads (TLP at 12 waves/CU covers the latency)
        const f32x4 a00 = *reinterpret_cast<const f32x4*>(xrow0 + s * 32);
        const f32x4 a01 = *reinterpret_cast<const f32x4*>(xrow0 + s * 32 + 4);
        const f32x4 a10 = *reinterpret_cast<const f32x4*>(xrow1 + s * 32);
        const f32x4 a11 = *reinterpret_cast<const f32x4*>(xrow1 + s * 32 + 4);

        // hi/lo split in-register
        half8 ah[2], al[2];
#pragma unroll
        for (int j = 0; j < 4; ++j) {
            const _Float16 h00 = (_Float16)a00[j];
            const _Float16 h01 = (_Float16)a01[j];
            const _Float16 h10 = (_Float16)a10[j];
            const _Float16 h11 = (_Float16)a11[j];
            ah[0][j]     = h00;
            ah[0][4 + j] = h01;
            ah[1][j]     = h10;
            ah[1][4 + j] = h11;
            al[0][j]     = (_Float16)((a00[j] - (float)h00) * LO_SCALE);
            al[0][4 + j] = (_Float16)((a01[j] - (float)h01) * LO_SCALE);
            al[1][j]     = (_Float16)((a10[j] - (float)h10) * LO_SCALE);
            al[1][4 + j] = (_Float16)((a11[j] - (float)h11) * LO_SCALE);
        }

        // 24 MFMA
#pragma unroll
        for (int g = 0; g < 4; ++g)
#pragma unroll
            for (int ms = 0; ms < 2; ++ms) {
                acc[ms][g]  = __builtin_amdgcn_mfma_f32_16x16x32_f16(ah[ms], bh[g], acc[ms][g],  0, 0, 0);
                acc2[ms][g] = __builtin_amdgcn_mfma_f32_16x16x32_f16(ah[ms], bl[g], acc2[ms][g], 0, 0, 0);
                acc2[ms][g] = __builtin_amdgcn_mfma_f32_16x16x32_f16(al[ms], bh[g], acc2[ms][g], 0, 0, 0);
            }
    }

    // ---- exchange via LDS: combine planes per kh, sum over kh in reader ----
#pragma unroll
    for (int ms = 0; ms < 2; ++ms)
#pragma unroll
        for (int g = 0; g < 4; ++g)
            red[kh][eh][ms][g][l] = acc[ms][g] + acc2[ms][g] * LO_INV;
    __syncthreads();

    // ---- epilogue: wave handles M-subtile ms_w, rows r0,r0+1 ----
    const int ms_w = W >> 1;
    const int r0   = 2 * (W & 1);
    const int grp  = l >> 4;
    const int ln16 = l & 15;
    const float NEG = -__builtin_inff();

    f32x4 v[8];
#pragma unroll
    for (int f = 0; f < 8; ++f)
        v[f] = red[0][f >> 2][ms_w][f & 3][l] + red[1][f >> 2][ms_w][f & 3][l];

#pragma unroll
    for (int rr = 0; rr < 4; ++rr) {
        if (rr != r0 && rr != r0 + 1) continue;   // wave-uniform skip
        const int t = t0 + ms_w * 16 + 4 * grp + rr;
        float vr[8];
#pragma unroll
        for (int f = 0; f < 8; ++f) {
            vr[f] = v[f][rr];
            logits[(size_t)t * NEXP + 16 * f + ln16] = vr[f];
        }

        unsigned selm = 0u;
        int   mycand = 0;
        float mycv   = 0.0f;
#pragma unroll
        for (int k = 0; k < NCAND; ++k) {
            float lv = NEG; int le = 0;
#pragma unroll
            for (int f = 0; f < 8; ++f) {
                const float c = ((selm >> f) & 1u) ? NEG : vr[f];
                if (c > lv) { lv = c; le = 16 * f + ln16; }   // asc f => lower id on tie
            }
            float cv = lv; int ce = le;
#pragma unroll
            for (int off = 8; off > 0; off >>= 1) {
                const float ov = __shfl_xor(cv, off, 16);
                const int   oe = __shfl_xor(ce, off, 16);
                if (ov > cv || (ov == cv && oe < ce)) { cv = ov; ce = oe; }
            }
            if (ln16 == k) { mycand = ce; mycv = cv; }
            if ((ce & 15) == ln16) selm |= 1u << (ce >> 4);
        }

        // gap certification over ranks 0..8
        const float nv = __shfl(mycv, ln16 + 1, 16);
        int fl = (ln16 <= 8 && (mycv - nv) < DELTA_GAP) ? 1 : 0;
#pragma unroll
        for (int off = 8; off > 0; off >>= 1)
            fl |= __shfl_xor(fl, off, 16);

        // normalized top-8 probs (softmax denom cancels in renorm)
        const float m = __shfl(mycv, 0, 16);
        const float p = (ln16 < KSEL) ? expf(mycv - m) : 0.0f;
        float ps = p;
#pragma unroll
        for (int off = 8; off > 0; off >>= 1)
            ps += __shfl_xor(ps, off, 16);

        cand[(size_t)t * NCAND + ln16] = mycand;
        if (ln16 < KSEL) {
            topv[(size_t)t * KSEL + ln16] = p / ps;
            topi[(size_t)t * KSEL + ln16] = (float)mycand;
        }
        if (ln16 == 0) flag[t] = fl;
    }
}

// ===========================================================================
// Kernel 2: fp64 refine of flagged tokens (~250 expected at DELTA=1e-4).
// x kept in f32 registers (32 regs, no spill); cvt per use. 4 independent
// FMA chains per candidate; fixed combine order = deterministic.
// ===========================================================================
__global__ __launch_bounds__(256) void refine_flagged(
    const float* __restrict__ x, const float* __restrict__ w,
    const int* __restrict__ cand, const int* __restrict__ flag,
    float* __restrict__ topv, float* __restrict__ topi)
{
    const int l = threadIdx.x & 63;
    const int t = (int)((blockIdx.x * 256u + threadIdx.x) >> 6);
    if (!flag[t]) return;   // wave-uniform

    const int myid = cand[(size_t)t * NCAND + (l & 15)];
    const float* xrow = x + (size_t)t * HDIM;

    f32x4 xv[8];
#pragma unroll
    for (int i = 0; i < 8; ++i)
        xv[i] = *reinterpret_cast<const f32x4*>(xrow + i * 256 + l * 4);

    double part[NCAND];
    int    cid[NCAND];
#pragma unroll
    for (int c = 0; c < NCAND; ++c) {
        const int eid = __shfl(myid, c);
        cid[c] = eid;
        const float* wrow = w + (size_t)eid * HDIM;
        double s0 = 0.0, s1 = 0.0, s2 = 0.0, s3 = 0.0;
#pragma unroll
        for (int i = 0; i < 8; ++i) {
            const f32x4 wv4 = *reinterpret_cast<const f32x4*>(wrow + i * 256 + l * 4);
            s0 = fma((double)xv[i][0], (double)wv4[0], s0);
            s1 = fma((double)xv[i][1], (double)wv4[1], s1);
            s2 = fma((double)xv[i][2], (double)wv4[2], s2);
            s3 = fma((double)xv[i][3], (double)wv4[3], s3);
        }
        part[c] = (s0 + s1) + (s2 + s3);
    }

#pragma unroll
    for (int off = 32; off > 0; off >>= 1)
#pragma unroll
        for (int c = 0; c < NCAND; ++c)
            part[c] += __shfl_xor(part[c], off);

    unsigned selm = 0u;
    double m = 0.0, kv = 0.0;
    int ki = 0;
    float psum = 0.0f;
#pragma unroll
    for (int k = 0; k < KSEL; ++k) {
        double bv = -__builtin_inf(); int bi = 0x7fffffff; int bc = 0;
#pragma unroll
        for (int c = 0; c < NCAND; ++c) {
            if (!((selm >> c) & 1u)) {
                if (part[c] > bv || (part[c] == bv && cid[c] < bi)) {
                    bv = part[c]; bi = cid[c]; bc = c;
                }
            }
        }
        if (k == 0) m = bv;
        psum += expf((float)(bv - m));
        if (l == k) { kv = bv; ki = bi; }
        selm |= 1u << bc;
    }

    if (l < KSEL) {
        topv[(size_t)t * KSEL + l] = expf((float)(kv - m)) / psum;
        topi[(size_t)t * KSEL + l] = (float)ki;
    }
}

// ===========================================================================
// Fallback (ws too small): proven round-2 fused fp64 kernel.
// ===========================================================================
#define BM 64
#define BK 32
#define BSTRIDE (BK + 4)
__global__ __launch_bounds__(256) void router_fused(
    const float* __restrict__ x, const float* __restrict__ w,
    float* __restrict__ logits, float* __restrict__ topv, float* __restrict__ topi)
{
    __shared__ float Bs[NEXP][BSTRIDE];
    const int tid = threadIdx.x;
    const int tn = tid & 15, tm = tid >> 4;
    const int row0 = blockIdx.x * BM;
    const int kc = tid & 7, cr = tid >> 3;

    double acc[4][8];
#pragma unroll
    for (int i = 0; i < 4; ++i)
#pragma unroll
        for (int j = 0; j < 8; ++j) acc[i][j] = 0.0;

    const float* xp[4];
#pragma unroll
    for (int i = 0; i < 4; ++i) xp[i] = x + (size_t)(row0 + tm + 16 * i) * HDIM;

    float4 rb[4];
#pragma unroll
    for (int p = 0; p < 4; ++p)
        rb[p] = *reinterpret_cast<const float4*>(&w[(size_t)(cr + 32 * p) * HDIM + kc * 4]);

    for (int k0 = 0; k0 < HDIM; k0 += BK) {
        __syncthreads();
#pragma unroll
        for (int p = 0; p < 4; ++p)
            *reinterpret_cast<float4*>(&Bs[cr + 32 * p][kc * 4]) = rb[p];
        __syncthreads();
        if (k0 + BK < HDIM) {
#pragma unroll
            for (int p = 0; p < 4; ++p)
                rb[p] = *reinterpret_cast<const float4*>(
                    &w[(size_t)(cr + 32 * p) * HDIM + (k0 + BK) + kc * 4]);
        }
#pragma unroll 4
        for (int k4 = 0; k4 < BK; k4 += 4) {
            float4 a4[4], b4[8];
#pragma unroll
            for (int i = 0; i < 4; ++i)
                a4[i] = *reinterpret_cast<const float4*>(&xp[i][k0 + k4]);
#pragma unroll
            for (int j = 0; j < 8; ++j)
                b4[j] = *reinterpret_cast<const float4*>(&Bs[tn + 16 * j][k4]);
#pragma unroll
            for (int kk = 0; kk < 4; ++kk) {
                double bd[8];
#pragma unroll
                for (int j = 0; j < 8; ++j) bd[j] = (double)((const float*)&b4[j])[kk];
#pragma unroll
                for (int i = 0; i < 4; ++i) {
                    const double ad = (double)((const float*)&a4[i])[kk];
#pragma unroll
                    for (int j = 0; j < 8; ++j) acc[i][j] = fma(ad, bd[j], acc[i][j]);
                }
            }
        }
    }
#pragma unroll
    for (int i = 0; i < 4; ++i) {
        float* orow = logits + (size_t)(row0 + tm + 16 * i) * NEXP;
#pragma unroll
        for (int j = 0; j < 8; ++j) orow[tn + 16 * j] = (float)acc[i][j];
    }
    for (int i = 0; i < 4; ++i) {
        const int t = row0 + tm + 16 * i;
        unsigned sel = 0u;
        double m = 0.0, kv = 0.0;
        int ki = 0;
        const double NEGD = -__builtin_inf();
#pragma unroll
        for (int k = 0; k < KSEL; ++k) {
            double lv = NEGD; int le = 0;
#pragma unroll
            for (int j = 0; j < 8; ++j) {
                const double v = (sel >> j) & 1u ? NEGD : acc[i][j];
                if (v > lv) { lv = v; le = tn + 16 * j; }
            }
            double cv = lv; int ce = le;
#pragma unroll
            for (int off = 8; off > 0; off >>= 1) {
                const double ov = __shfl_xor(cv, off, 16);
                const int    oe = __shfl_xor(ce, off, 16);
                if (ov > cv || (ov == cv && oe < ce)) { cv = ov; ce = oe; }
            }
            if (k == 0) m = cv;
            if (tn == k) { kv = cv; ki = ce; }
            if ((ce & 15) == tn) sel |= 1u << (ce >> 4);
        }
        float z = 0.0f;
#pragma unroll
        for (int j = 0; j < 8; ++j) z += expf((float)(acc[i][j] - m));
#pragma unroll
        for (int off = 8; off > 0; off >>= 1) z += __shfl_xor(z, off, 16);
        const float p = (tn < KSEL) ? expf((float)(kv - m)) / z : 0.0f;
        float ps = p;
#pragma unroll
        for (int off = 8; off > 0; off >>= 1) ps += __shfl_xor(ps, off, 16);
        if (tn < KSEL) {
            topv[(size_t)t * KSEL + tn] = p / ps;
            topi[(size_t)t * KSEL + tn] = (float)ki;
        }
    }
}

extern "C" void kernel_launch(void* const* d_in, const int* in_sizes, int n_in,
                              void* d_out, int out_size, void* d_ws, size_t ws_size,
                              hipStream_t stream) {
    const float* x = (const float*)d_in[0];   // [16384, 2048]
    const float* w = (const float*)d_in[1];   // [128, 2048]

    float* out    = (float*)d_out;
    float* logits = out;                                   // 16384*128
    float* topv   = out + (size_t)NTOK * NEXP;             // 16384*8
    float* topi   = topv + (size_t)NTOK * KSEL;            // 16384*8

    // ws layout: whp[512KB] | wlp[512KB] | cand[1MB] | flag[64KB]
    const size_t plane = (size_t)NEXP * HDIM;              // 262144 halfwords
    const size_t need  = plane * 2 * sizeof(_Float16)
                       + (size_t)NTOK * NCAND * sizeof(int)
                       + (size_t)NTOK * sizeof(int);
    if (ws_size >= need) {
        _Float16* whp = (_Float16*)d_ws;
        _Float16* wlp = whp + plane;
        int* cand = (int*)(wlp + plane);
        int* flag = cand + (size_t)NTOK * NCAND;
        w_convert<<<NEXP, 256, 0, stream>>>(w, whp, wlp);
        gemm3_split<<<NTOK / 32, 256, 0, stream>>>(x, whp, wlp, logits, topv, topi, cand, flag);
        refine_flagged<<<NTOK / 4, 256, 0, stream>>>(x, w, cand, flag, topv, topi);
    } else {
        router_fused<<<NTOK / BM, 256, 0, stream>>>(x, w, logits, topv, topi);
    }
}

// Round 16
// 115.556 us; speedup vs baseline: 1.0024x; 1.0024x over previous
//
#include <hip/hip_runtime.h>
#include <hip/hip_bf16.h>
#include <hip/hip_fp16.h>

#define NTOK 16384
#define HDIM 2048
#define NEXP 128
#define KSEL 8
#define NCAND 16
#define DELTA_GAP 4e-3f     // hi-only fp16: gap-err sigma ~5e-4 -> 8 sigma; ~50% flagged
#define REFINE_GRID 2048

typedef _Float16 half8  __attribute__((ext_vector_type(8)));
typedef float    f32x4  __attribute__((ext_vector_type(4)));

// ===========================================================================
// Kernel 0: W fp32 -> fragment-major fp16 HI plane (512 KB, L2-hot) + zero
// the compaction counter. Fragment (ks, eg): halfword
// ((ks*8+eg)*64+l)*8+j = w[16*eg + (l&15)][32*ks + 8*(l>>4) + j] (proven R4-R15).
// ===========================================================================
__global__ __launch_bounds__(256) void w_convert(
    const float* __restrict__ w, _Float16* __restrict__ whp, int* __restrict__ counter)
{
    if (blockIdx.x == 0 && threadIdx.x == 0) counter[0] = 0;
    const int e = blockIdx.x;            // 0..127
    const int k = threadIdx.x * 8;       // 0..2040
    const float* src = w + (size_t)e * HDIM + k;
    const f32x4 v0 = *reinterpret_cast<const f32x4*>(src);
    const f32x4 v1 = *reinterpret_cast<const f32x4*>(src + 4);
    half8 h;
#pragma unroll
    for (int j = 0; j < 4; ++j) {
        h[j]     = (_Float16)v0[j];
        h[4 + j] = (_Float16)v1[j];
    }
    const int ks = k >> 5;
    const int eg = e >> 4;
    const int l  = (e & 15) | (((k >> 3) & 3) << 4);
    *reinterpret_cast<half8*>(whp + ((size_t)(ks * 8 + eg) * 64 + l) * 8) = h;
}

// ===========================================================================
// Kernel 1 (VERBATIM R11, measured ~45 us): single-product fp16 MFMA GEMM,
// no LDS/barriers in K-loop. Grid 1024 x 256 thr = 4 waves; wave = 16 tokens
// x 128 experts x one K-quarter -> 16 waves/CU TLP. Epilogue: 32KB LDS
// cross-q reduce + top-16 + gap certification (4e-3) + top-8 probs.
// ===========================================================================
__global__ __launch_bounds__(256, 3) void gemm1_fused(
    const float* __restrict__ x, const _Float16* __restrict__ whp,
    float* __restrict__ logits, float* __restrict__ topv, float* __restrict__ topi,
    int* __restrict__ cand, int* __restrict__ flag)
{
    __shared__ f32x4 red[4][8][64];   // [q][eg][lane] = 32 KB

    const int tid = threadIdx.x;
    const int l   = tid & 63;
    const int q   = tid >> 6;         // wave = K-quarter 0..3
    const int t0  = blockIdx.x * 16;

    const float* xrow = x + (size_t)(t0 + (l & 15)) * HDIM + q * 512 + 8 * (l >> 4);
    const _Float16* wq = whp + (size_t)q * 16 * 8 * 512;

    f32x4 acc[8];
#pragma unroll
    for (int eg = 0; eg < 8; ++eg) acc[eg] = (f32x4){0.f, 0.f, 0.f, 0.f};

#define LOADA(A, S)                                                        \
    {                                                                      \
        A[0] = *reinterpret_cast<const f32x4*>(xrow + (S) * 32);           \
        A[1] = *reinterpret_cast<const f32x4*>(xrow + (S) * 32 + 4);       \
    }
#define LOADB(B, S)                                                        \
    {                                                                      \
        _Pragma("unroll")                                                  \
        for (int eg_ = 0; eg_ < 8; ++eg_)                                  \
            B[eg_] = *reinterpret_cast<const half8*>(                      \
                wq + ((size_t)(S) * 8 + eg_) * 512 + l * 8);               \
    }
#define CVTA(AH, A)                                                        \
    {                                                                      \
        _Pragma("unroll")                                                  \
        for (int j_ = 0; j_ < 4; ++j_) {                                   \
            AH[j_]     = (_Float16)A[0][j_];                               \
            AH[4 + j_] = (_Float16)A[1][j_];                               \
        }                                                                  \
    }
#define MFMA8(AH, B)                                                       \
    {                                                                      \
        _Pragma("unroll")                                                  \
        for (int eg_ = 0; eg_ < 8; ++eg_)                                  \
            acc[eg_] = __builtin_amdgcn_mfma_f32_16x16x32_f16(             \
                AH, B[eg_], acc[eg_], 0, 0, 0);                            \
    }

    f32x4 a0[2], a1[2];
    half8 b0[8], b1[8];

    LOADA(a0, 0) LOADB(b0, 0)
    for (int s = 0; s < 16; s += 2) {
        LOADA(a1, s + 1) LOADB(b1, s + 1)
        {
            half8 ah; CVTA(ah, a0) MFMA8(ah, b0)
        }
        if (s + 2 < 16) { LOADA(a0, s + 2) LOADB(b0, s + 2) }
        {
            half8 ah; CVTA(ah, a1) MFMA8(ah, b1)
        }
    }
#undef LOADA
#undef LOADB
#undef CVTA
#undef MFMA8

    // ---- cross-q reduction: one LDS pass, fixed order (deterministic) ----
#pragma unroll
    for (int eg = 0; eg < 8; ++eg)
        red[q][eg][l] = acc[eg];
    __syncthreads();

    f32x4 v[8];
#pragma unroll
    for (int eg = 0; eg < 8; ++eg) {
        f32x4 s0 = red[0][eg][l];
        s0 += red[1][eg][l];
        s0 += red[2][eg][l];
        s0 += red[3][eg][l];
        v[eg] = s0;
    }

    // ---- this wave handles token row rr = q of each 4-row group ----
    const int grp  = l >> 4;
    const int ln16 = l & 15;
    const int t    = t0 + 4 * grp + q;
    const float NEG = -__builtin_inff();

    float vr[8];
#pragma unroll
    for (int f = 0; f < 8; ++f) {
        const f32x4 t4 = v[f];
        vr[f] = (q == 0) ? t4[0] : (q == 1) ? t4[1] : (q == 2) ? t4[2] : t4[3];
        logits[(size_t)t * NEXP + 16 * f + ln16] = vr[f];
    }

    unsigned selm = 0u;
    int   mycand = 0;
    float mycv   = 0.0f;
#pragma unroll
    for (int k = 0; k < NCAND; ++k) {
        float lv = NEG; int le = 0;
#pragma unroll
        for (int f = 0; f < 8; ++f) {
            const float c = ((selm >> f) & 1u) ? NEG : vr[f];
            if (c > lv) { lv = c; le = 16 * f + ln16; }   // asc f => lower id on tie
        }
        float cv = lv; int ce = le;
#pragma unroll
        for (int off = 8; off > 0; off >>= 1) {
            const float ov = __shfl_xor(cv, off, 16);
            const int   oe = __shfl_xor(ce, off, 16);
            if (ov > cv || (ov == cv && oe < ce)) { cv = ov; ce = oe; }
        }
        if (ln16 == k) { mycand = ce; mycv = cv; }
        if ((ce & 15) == ln16) selm |= 1u << (ce >> 4);
    }

    // gap certification over ranks 0..8
    const float nv = __shfl(mycv, ln16 + 1, 16);
    int fl = (ln16 <= 8 && (mycv - nv) < DELTA_GAP) ? 1 : 0;
#pragma unroll
    for (int off = 8; off > 0; off >>= 1)
        fl |= __shfl_xor(fl, off, 16);

    const float m = __shfl(mycv, 0, 16);
    const float p = (ln16 < KSEL) ? expf(mycv - m) : 0.0f;
    float ps = p;
#pragma unroll
    for (int off = 8; off > 0; off >>= 1)
        ps += __shfl_xor(ps, off, 16);

    cand[(size_t)t * NCAND + ln16] = mycand;
    if (ln16 < KSEL) {
        topv[(size_t)t * KSEL + ln16] = p / ps;
        topi[(size_t)t * KSEL + ln16] = (float)mycand;
    }
    if (ln16 == 0) flag[t] = fl;
}

// ===========================================================================
// Kernel 2: ballot-compact flagged token ids into a dense list.
// Set is input-deterministic; order is not, but refine writes are per-token
// -> final output deterministic.
// ===========================================================================
__global__ __launch_bounds__(256) void compact_flags(
    const int* __restrict__ flag, int* __restrict__ counter, int* __restrict__ list)
{
    const int t = blockIdx.x * 256 + threadIdx.x;
    const int lane = threadIdx.x & 63;
    const bool f = flag[t] != 0;
    const unsigned long long mask = __ballot(f);
    int base = 0;
    if (lane == 0) base = atomicAdd(counter, (int)__popcll(mask));
    base = __shfl(base, 0);
    if (f) list[base + __popcll(mask & ((1ull << lane) - 1ull))] = t;
}

// ===========================================================================
// Kernel 3: compacted fp64 refine. Fixed grid 2048 blocks x 4 waves;
// block handles tokens list[bid], list[bid+2048], ... One BLOCK per token:
// wave wv refines candidates 4wv..4wv+3 (4 independent fp64 chains each,
// butterfly reduce), LDS-merge 16 refined values, wave 0 runs the proven
// width-16 top-8 + normalized probs.
// ===========================================================================
__global__ __launch_bounds__(256) void refine2(
    const float* __restrict__ x, const float* __restrict__ w,
    const int* __restrict__ cand, const int* __restrict__ counter,
    const int* __restrict__ list,
    float* __restrict__ topv, float* __restrict__ topi)
{
    __shared__ double sval[16];
    __shared__ int    sid[16];

    const int tid  = threadIdx.x;
    const int l    = tid & 63;
    const int wv   = tid >> 6;
    const int n    = counter[0];

    for (int i = blockIdx.x; i < n; i += REFINE_GRID) {
        const int t = list[i];
        const float* xrow = x + (size_t)t * HDIM;

        f32x4 xv[8];
#pragma unroll
        for (int j = 0; j < 8; ++j)
            xv[j] = *reinterpret_cast<const f32x4*>(xrow + j * 256 + l * 4);

        double part[4];
        int    cid[4];
#pragma unroll
        for (int c = 0; c < 4; ++c) {
            const int eid = cand[(size_t)t * NCAND + wv * 4 + c];  // wave-uniform
            cid[c] = eid;
            const float* wrow = w + (size_t)eid * HDIM;
            double s0 = 0.0, s1 = 0.0, s2 = 0.0, s3 = 0.0;
#pragma unroll
            for (int j = 0; j < 8; ++j) {
                const f32x4 wv4 = *reinterpret_cast<const f32x4*>(wrow + j * 256 + l * 4);
                s0 = fma((double)xv[j][0], (double)wv4[0], s0);
                s1 = fma((double)xv[j][1], (double)wv4[1], s1);
                s2 = fma((double)xv[j][2], (double)wv4[2], s2);
                s3 = fma((double)xv[j][3], (double)wv4[3], s3);
            }
            double d = (s0 + s1) + (s2 + s3);
#pragma unroll
            for (int off = 32; off > 0; off >>= 1)
                d += __shfl_xor(d, off);
            part[c] = d;   // identical in all lanes (fixed butterfly order)
        }

        // merge: lane c (c<4) writes candidate 4wv+c
        {
            const double v = (l == 0) ? part[0] : (l == 1) ? part[1]
                            : (l == 2) ? part[2] : part[3];
            const int    id = (l == 0) ? cid[0] : (l == 1) ? cid[1]
                            : (l == 2) ? cid[2] : cid[3];
            if (l < 4) { sval[wv * 4 + l] = v; sid[wv * 4 + l] = id; }
        }
        __syncthreads();

        if (wv == 0) {
            const double NEGD = -__builtin_inf();
            const double myv = (l < 16) ? sval[l] : NEGD;
            const int    myi = (l < 16) ? sid[l]  : 0x7fffffff;

            bool sel = false;
            double m = 0.0, kv = 0.0;
            int ki = 0;
            float psum = 0.0f;
#pragma unroll
            for (int k = 0; k < KSEL; ++k) {
                double cv = sel ? NEGD : myv;
                int    ce = myi;
#pragma unroll
                for (int off = 8; off > 0; off >>= 1) {
                    const double ov = __shfl_xor(cv, off, 16);
                    const int    oe = __shfl_xor(ce, off, 16);
                    if (ov > cv || (ov == cv && oe < ce)) { cv = ov; ce = oe; }
                }
                if (k == 0) m = cv;
                psum += expf((float)(cv - m));
                if ((l & 15) == k) { kv = cv; ki = ce; }
                if (ce == myi && !sel) sel = true;   // owner lane marks selected
            }

            if (l < KSEL) {
                topv[(size_t)t * KSEL + l] = expf((float)(kv - m)) / psum;
                topi[(size_t)t * KSEL + l] = (float)ki;
            }
        }
        __syncthreads();   // sval reused next iteration
    }
}

// ===========================================================================
// Fallback (ws too small): proven round-2 fused fp64 kernel.
// ===========================================================================
#define BM 64
#define BK 32
#define BSTRIDE (BK + 4)
__global__ __launch_bounds__(256) void router_fused(
    const float* __restrict__ x, const float* __restrict__ w,
    float* __restrict__ logits, float* __restrict__ topv, float* __restrict__ topi)
{
    __shared__ float Bs[NEXP][BSTRIDE];
    const int tid = threadIdx.x;
    const int tn = tid & 15, tm = tid >> 4;
    const int row0 = blockIdx.x * BM;
    const int kc = tid & 7, cr = tid >> 3;

    double acc[4][8];
#pragma unroll
    for (int i = 0; i < 4; ++i)
#pragma unroll
        for (int j = 0; j < 8; ++j) acc[i][j] = 0.0;

    const float* xp[4];
#pragma unroll
    for (int i = 0; i < 4; ++i) xp[i] = x + (size_t)(row0 + tm + 16 * i) * HDIM;

    float4 rb[4];
#pragma unroll
    for (int p = 0; p < 4; ++p)
        rb[p] = *reinterpret_cast<const float4*>(&w[(size_t)(cr + 32 * p) * HDIM + kc * 4]);

    for (int k0 = 0; k0 < HDIM; k0 += BK) {
        __syncthreads();
#pragma unroll
        for (int p = 0; p < 4; ++p)
            *reinterpret_cast<float4*>(&Bs[cr + 32 * p][kc * 4]) = rb[p];
        __syncthreads();
        if (k0 + BK < HDIM) {
#pragma unroll
            for (int p = 0; p < 4; ++p)
                rb[p] = *reinterpret_cast<const float4*>(
                    &w[(size_t)(cr + 32 * p) * HDIM + (k0 + BK) + kc * 4]);
        }
#pragma unroll 4
        for (int k4 = 0; k4 < BK; k4 += 4) {
            float4 a4[4], b4[8];
#pragma unroll
            for (int i = 0; i < 4; ++i)
                a4[i] = *reinterpret_cast<const float4*>(&xp[i][k0 + k4]);
#pragma unroll
            for (int j = 0; j < 8; ++j)
                b4[j] = *reinterpret_cast<const float4*>(&Bs[tn + 16 * j][k4]);
#pragma unroll
            for (int kk = 0; kk < 4; ++kk) {
                double bd[8];
#pragma unroll
                for (int j = 0; j < 8; ++j) bd[j] = (double)((const float*)&b4[j])[kk];
#pragma unroll
                for (int i = 0; i < 4; ++i) {
                    const double ad = (double)((const float*)&a4[i])[kk];
#pragma unroll
                    for (int j = 0; j < 8; ++j) acc[i][j] = fma(ad, bd[j], acc[i][j]);
                }
            }
        }
    }
#pragma unroll
    for (int i = 0; i < 4; ++i) {
        float* orow = logits + (size_t)(row0 + tm + 16 * i) * NEXP;
#pragma unroll
        for (int j = 0; j < 8; ++j) orow[tn + 16 * j] = (float)acc[i][j];
    }
    for (int i = 0; i < 4; ++i) {
        const int t = row0 + tm + 16 * i;
        unsigned sel = 0u;
        double m = 0.0, kv = 0.0;
        int ki = 0;
        const double NEGD = -__builtin_inf();
#pragma unroll
        for (int k = 0; k < KSEL; ++k) {
            double lv = NEGD; int le = 0;
#pragma unroll
            for (int j = 0; j < 8; ++j) {
                const double v = (sel >> j) & 1u ? NEGD : acc[i][j];
                if (v > lv) { lv = v; le = tn + 16 * j; }
            }
            double cv = lv; int ce = le;
#pragma unroll
            for (int off = 8; off > 0; off >>= 1) {
                const double ov = __shfl_xor(cv, off, 16);
                const int    oe = __shfl_xor(ce, off, 16);
                if (ov > cv || (ov == cv && oe < ce)) { cv = ov; ce = oe; }
            }
            if (k == 0) m = cv;
            if (tn == k) { kv = cv; ki = ce; }
            if ((ce & 15) == tn) sel |= 1u << (ce >> 4);
        }
        float z = 0.0f;
#pragma unroll
        for (int j = 0; j < 8; ++j) z += expf((float)(acc[i][j] - m));
#pragma unroll
        for (int off = 8; off > 0; off >>= 1) z += __shfl_xor(z, off, 16);
        const float p = (tn < KSEL) ? expf((float)(kv - m)) / z : 0.0f;
        float ps = p;
#pragma unroll
        for (int off = 8; off > 0; off >>= 1) ps += __shfl_xor(ps, off, 16);
        if (tn < KSEL) {
            topv[(size_t)t * KSEL + tn] = p / ps;
            topi[(size_t)t * KSEL + tn] = (float)ki;
        }
    }
}

extern "C" void kernel_launch(void* const* d_in, const int* in_sizes, int n_in,
                              void* d_out, int out_size, void* d_ws, size_t ws_size,
                              hipStream_t stream) {
    const float* x = (const float*)d_in[0];   // [16384, 2048]
    const float* w = (const float*)d_in[1];   // [128, 2048]

    float* out    = (float*)d_out;
    float* logits = out;                                   // 16384*128
    float* topv   = out + (size_t)NTOK * NEXP;             // 16384*8
    float* topi   = topv + (size_t)NTOK * KSEL;            // 16384*8

    // ws layout: whp[512KB] | cand[1MB] | flag[64KB] | counter[64B] | list[64KB]
    const size_t plane = (size_t)NEXP * HDIM;              // 262144 halfwords
    const size_t need  = plane * sizeof(_Float16)
                       + (size_t)NTOK * NCAND * sizeof(int)
                       + (size_t)NTOK * sizeof(int)
                       + 64
                       + (size_t)NTOK * sizeof(int);
    if (ws_size >= need) {
        _Float16* whp   = (_Float16*)d_ws;
        int* cand       = (int*)(whp + plane);
        int* flag       = cand + (size_t)NTOK * NCAND;
        int* counter    = flag + NTOK;
        int* list       = counter + 16;
        w_convert<<<NEXP, 256, 0, stream>>>(w, whp, counter);
        gemm1_fused<<<NTOK / 16, 256, 0, stream>>>(x, whp, logits, topv, topi, cand, flag);
        compact_flags<<<NTOK / 256, 256, 0, stream>>>(flag, counter, list);
        refine2<<<REFINE_GRID, 256, 0, stream>>>(x, w, cand, counter, list, topv, topi);
    } else {
        router_fused<<<NTOK / BM, 256, 0, stream>>>(x, w, logits, topv, topi);
    }
}

// Round 19
// 90.968 us; speedup vs baseline: 1.2733x; 1.2703x over previous
//
#include <hip/hip_runtime.h>
#include <hip/hip_bf16.h>
#include <hip/hip_fp16.h>

#define NTOK 16384
#define HDIM 2048
#define NEXP 128
#define KSEL 8
#define NCAND 16
#define DELTA_GAP 1e-4f     // 3-product err sigma ~1e-6; np-ref err ~2.5e-5; proven R5-R16
#define LO_SCALE 2048.0f
#define LO_INV (1.0f/2048.0f)

typedef _Float16 half8  __attribute__((ext_vector_type(8)));
typedef float    f32x4  __attribute__((ext_vector_type(4)));

// ===========================================================================
// Kernel 0: W fp32 -> fragment-major fp16 hi/lo planes (once, 1 MB, L2-hot).
// Fragment (ks, eg): halfword ((ks*8+eg)*64+l)*8+j =
// w[16*eg + (l&15)][32*ks + 8*(l>>4) + j]  (layout proven rounds 4-16).
// ===========================================================================
__global__ __launch_bounds__(256) void w_convert(
    const float* __restrict__ w, _Float16* __restrict__ whp, _Float16* __restrict__ wlp)
{
    const int e = blockIdx.x;
    const int k = threadIdx.x * 8;
    const float* src = w + (size_t)e * HDIM + k;
    const f32x4 v0 = *reinterpret_cast<const f32x4*>(src);
    const f32x4 v1 = *reinterpret_cast<const f32x4*>(src + 4);
    float vv[8] = {v0[0], v0[1], v0[2], v0[3], v1[0], v1[1], v1[2], v1[3]};
    half8 h, lo;
#pragma unroll
    for (int j = 0; j < 8; ++j) {
        const _Float16 hj = (_Float16)vv[j];
        h[j]  = hj;
        lo[j] = (_Float16)((vv[j] - (float)hj) * LO_SCALE);
    }
    const int ks = k >> 5;
    const int eg = e >> 4;
    const int l  = (e & 15) | (((k >> 3) & 3) << 4);
    const size_t di = ((size_t)(ks * 8 + eg) * 64 + l) * 8;
    *reinterpret_cast<half8*>(whp + di) = h;
    *reinterpret_cast<half8*>(wlp + di) = lo;
}

// ===========================================================================
// Kernel 1: split-fp16 3-product MFMA GEMM, asm load pipeline, RACE-PROOFED:
// - Expert-split geometry (R15, proven): wave = 32 tok x 64 exp (eh) x one
//   K-half (kh, 32 steps of 32k). acc+acc2 = 64 regs; total ~200/256 ->
//   regalloc has slack, no live-range splits (R17/R18's NaN mechanism:
//   copies of in-flight asm-load registers at ~250/256 pressure).
// - FULLY UNROLLED 32-step loop: no loop PHIs -> no back-edge copies.
// - Ledger: slot = 8 B-loads + 4 A-loads. Prologue slots 0,1 (24 out).
//   Per step: vmcnt(12) drains slot s exactly (slot s+1 stays in flight
//   across this step's 24 MFMA); loads for s+2 issue AFTER the MFMAs
//   (in-order issue => WAR-safe buffer reuse). Last step vmcnt(0).
// Epilogue (R15) + certify(1e-4) + refine (R12) proven.
// ===========================================================================
__global__ __launch_bounds__(256, 2) void gemm3_pipe(
    const float* __restrict__ x,
    const _Float16* __restrict__ whp, const _Float16* __restrict__ wlp,
    float* __restrict__ logits, float* __restrict__ topv, float* __restrict__ topi,
    int* __restrict__ cand, int* __restrict__ flag)
{
    __shared__ f32x4 red[2][2][2][4][64];   // [kh][eh][ms][g][lane] = 32 KB

    const int tid = threadIdx.x;
    const int l   = tid & 63;
    const int W   = tid >> 6;
    const int eh  = W & 1;           // expert half: eg = 4*eh + g
    const int kh  = W >> 1;          // K half
    const int t0  = blockIdx.x * 32;

    // A: lane covers rows t0+(l&15) / +16, k-octet 8*(l>>4) per 32-k step
    const char* xb0 = (const char*)(x + (size_t)(t0 + (l & 15)) * HDIM + kh * 1024 + 8 * (l >> 4));
    const char* xb1 = xb0 + (size_t)16 * HDIM * 4;
    // B chunk (ks, eg=4*eh+g) at byte ks*8192 + eh*4096 + g*1024; lane at +l*16
    const char* whB = (const char*)whp + (size_t)kh * 262144 + eh * 4096 + l * 16;
    const char* wlB = (const char*)wlp + (size_t)kh * 262144 + eh * 4096 + l * 16;

#define LDB(BH, BL, S)                                                                   \
    { const char* hb_ = whB + (size_t)(S) * 8192;                                        \
      const char* lb_ = wlB + (size_t)(S) * 8192;                                        \
      asm volatile("global_load_dwordx4 %0, %1, off"             : "=v"(BH[0]) : "v"(hb_)); \
      asm volatile("global_load_dwordx4 %0, %1, off offset:1024" : "=v"(BH[1]) : "v"(hb_)); \
      asm volatile("global_load_dwordx4 %0, %1, off offset:2048" : "=v"(BH[2]) : "v"(hb_)); \
      asm volatile("global_load_dwordx4 %0, %1, off offset:3072" : "=v"(BH[3]) : "v"(hb_)); \
      asm volatile("global_load_dwordx4 %0, %1, off"             : "=v"(BL[0]) : "v"(lb_)); \
      asm volatile("global_load_dwordx4 %0, %1, off offset:1024" : "=v"(BL[1]) : "v"(lb_)); \
      asm volatile("global_load_dwordx4 %0, %1, off offset:2048" : "=v"(BL[2]) : "v"(lb_)); \
      asm volatile("global_load_dwordx4 %0, %1, off offset:3072" : "=v"(BL[3]) : "v"(lb_)); }

#define LDA(AA, S)                                                                       \
    { const char* a0_ = xb0 + (S) * 128; const char* a1_ = xb1 + (S) * 128;              \
      asm volatile("global_load_dwordx4 %0, %1, off"            : "=v"(AA[0]) : "v"(a0_)); \
      asm volatile("global_load_dwordx4 %0, %1, off offset:16"  : "=v"(AA[1]) : "v"(a0_)); \
      asm volatile("global_load_dwordx4 %0, %1, off"            : "=v"(AA[2]) : "v"(a1_)); \
      asm volatile("global_load_dwordx4 %0, %1, off offset:16"  : "=v"(AA[3]) : "v"(a1_)); }

    f32x4 acc[2][4], acc2[2][4];
#pragma unroll
    for (int ms = 0; ms < 2; ++ms)
#pragma unroll
        for (int g = 0; g < 4; ++g) {
            acc[ms][g]  = (f32x4){0.f, 0.f, 0.f, 0.f};
            acc2[ms][g] = (f32x4){0.f, 0.f, 0.f, 0.f};
        }

    half8 bh[2][4], bl[2][4];
    f32x4 aa[2][4];
    half8 ah[2], al[2];

    // prologue: slots 0 and 1 in flight (24 outstanding)
    LDB(bh[0], bl[0], 0) LDA(aa[0], 0)
    LDB(bh[1], bl[1], 1) LDA(aa[1], 1)

#pragma unroll
    for (int s = 0; s < 32; ++s) {
        const int b = s & 1;

        if (s < 31) {
            asm volatile("s_waitcnt vmcnt(12)" ::: "memory");   // drain slot s exactly
        } else {
            asm volatile("s_waitcnt vmcnt(0)" ::: "memory");    // final slot
        }
        __builtin_amdgcn_sched_barrier(0);

        // A(s) hi/lo split in-register
#pragma unroll
        for (int j = 0; j < 4; ++j) {
            const _Float16 h00 = (_Float16)aa[b][0][j];
            const _Float16 h01 = (_Float16)aa[b][1][j];
            const _Float16 h10 = (_Float16)aa[b][2][j];
            const _Float16 h11 = (_Float16)aa[b][3][j];
            ah[0][j]     = h00;
            ah[0][4 + j] = h01;
            ah[1][j]     = h10;
            ah[1][4 + j] = h11;
            al[0][j]     = (_Float16)((aa[b][0][j] - (float)h00) * LO_SCALE);
            al[0][4 + j] = (_Float16)((aa[b][1][j] - (float)h01) * LO_SCALE);
            al[1][j]     = (_Float16)((aa[b][2][j] - (float)h10) * LO_SCALE);
            al[1][4 + j] = (_Float16)((aa[b][3][j] - (float)h11) * LO_SCALE);
        }

        // 24 MFMA (issue before next loads: in-order issue => WAR-safe)
#pragma unroll
        for (int g = 0; g < 4; ++g)
#pragma unroll
            for (int ms = 0; ms < 2; ++ms) {
                acc[ms][g]  = __builtin_amdgcn_mfma_f32_16x16x32_f16(ah[ms], bh[b][g], acc[ms][g],  0, 0, 0);
                acc2[ms][g] = __builtin_amdgcn_mfma_f32_16x16x32_f16(ah[ms], bl[b][g], acc2[ms][g], 0, 0, 0);
                acc2[ms][g] = __builtin_amdgcn_mfma_f32_16x16x32_f16(al[ms], bh[b][g], acc2[ms][g], 0, 0, 0);
            }
        __builtin_amdgcn_sched_barrier(0);

        if (s + 2 < 32) {
            LDB(bh[b], bl[b], s + 2)
            LDA(aa[b], s + 2)
        }
    }
#undef LDB
#undef LDA

    // ---- exchange via LDS (proven R15 epilogue) ----
#pragma unroll
    for (int ms = 0; ms < 2; ++ms)
#pragma unroll
        for (int g = 0; g < 4; ++g)
            red[kh][eh][ms][g][l] = acc[ms][g] + acc2[ms][g] * LO_INV;
    __syncthreads();

    const int ms_w = W >> 1;
    const int r0   = 2 * (W & 1);
    const int grp  = l >> 4;
    const int ln16 = l & 15;
    const float NEG = -__builtin_inff();

    f32x4 v[8];
#pragma unroll
    for (int f = 0; f < 8; ++f)
        v[f] = red[0][f >> 2][ms_w][f & 3][l] + red[1][f >> 2][ms_w][f & 3][l];

#pragma unroll
    for (int rr = 0; rr < 4; ++rr) {
        if (rr != r0 && rr != r0 + 1) continue;   // wave-uniform skip
        const int t = t0 + ms_w * 16 + 4 * grp + rr;
        float vr[8];
#pragma unroll
        for (int f = 0; f < 8; ++f) {
            vr[f] = v[f][rr];
            logits[(size_t)t * NEXP + 16 * f + ln16] = vr[f];
        }

        unsigned selm = 0u;
        int   mycand = 0;
        float mycv   = 0.0f;
#pragma unroll
        for (int k = 0; k < NCAND; ++k) {
            float lv = NEG; int le = 0;
#pragma unroll
            for (int f = 0; f < 8; ++f) {
                const float c = ((selm >> f) & 1u) ? NEG : vr[f];
                if (c > lv) { lv = c; le = 16 * f + ln16; }   // asc f => lower id on tie
            }
            float cv = lv; int ce = le;
#pragma unroll
            for (int off = 8; off > 0; off >>= 1) {
                const float ov = __shfl_xor(cv, off, 16);
                const int   oe = __shfl_xor(ce, off, 16);
                if (ov > cv || (ov == cv && oe < ce)) { cv = ov; ce = oe; }
            }
            if (ln16 == k) { mycand = ce; mycv = cv; }
            if ((ce & 15) == ln16) selm |= 1u << (ce >> 4);
        }

        // gap certification over ranks 0..8
        const float nv = __shfl(mycv, ln16 + 1, 16);
        int fl = (ln16 <= 8 && (mycv - nv) < DELTA_GAP) ? 1 : 0;
#pragma unroll
        for (int off = 8; off > 0; off >>= 1)
            fl |= __shfl_xor(fl, off, 16);

        // normalized top-8 probs (softmax denom cancels in renorm)
        const float m = __shfl(mycv, 0, 16);
        const float p = (ln16 < KSEL) ? expf(mycv - m) : 0.0f;
        float ps = p;
#pragma unroll
        for (int off = 8; off > 0; off >>= 1)
            ps += __shfl_xor(ps, off, 16);

        cand[(size_t)t * NCAND + ln16] = mycand;
        if (ln16 < KSEL) {
            topv[(size_t)t * KSEL + ln16] = p / ps;
            topi[(size_t)t * KSEL + ln16] = (float)mycand;
        }
        if (ln16 == 0) flag[t] = fl;
    }
}

// ===========================================================================
// Kernel 2: fp64 refine of flagged tokens (~250 expected at DELTA=1e-4).
// ===========================================================================
__global__ __launch_bounds__(256) void refine_flagged(
    const float* __restrict__ x, const float* __restrict__ w,
    const int* __restrict__ cand, const int* __restrict__ flag,
    float* __restrict__ topv, float* __restrict__ topi)
{
    const int l = threadIdx.x & 63;
    const int t = (int)((blockIdx.x * 256u + threadIdx.x) >> 6);
    if (!flag[t]) return;

    const int myid = cand[(size_t)t * NCAND + (l & 15)];
    const float* xrow = x + (size_t)t * HDIM;

    f32x4 xv[8];
#pragma unroll
    for (int i = 0; i < 8; ++i)
        xv[i] = *reinterpret_cast<const f32x4*>(xrow + i * 256 + l * 4);

    double part[NCAND];
    int    cid[NCAND];
#pragma unroll
    for (int c = 0; c < NCAND; ++c) {
        const int eid = __shfl(myid, c);
        cid[c] = eid;
        const float* wrow = w + (size_t)eid * HDIM;
        double s0 = 0.0, s1 = 0.0, s2 = 0.0, s3 = 0.0;
#pragma unroll
        for (int i = 0; i < 8; ++i) {
            const f32x4 wv4 = *reinterpret_cast<const f32x4*>(wrow + i * 256 + l * 4);
            s0 = fma((double)xv[i][0], (double)wv4[0], s0);
            s1 = fma((double)xv[i][1], (double)wv4[1], s1);
            s2 = fma((double)xv[i][2], (double)wv4[2], s2);
            s3 = fma((double)xv[i][3], (double)wv4[3], s3);
        }
        part[c] = (s0 + s1) + (s2 + s3);
    }

#pragma unroll
    for (int off = 32; off > 0; off >>= 1)
#pragma unroll
        for (int c = 0; c < NCAND; ++c)
            part[c] += __shfl_xor(part[c], off);

    unsigned selm = 0u;
    double m = 0.0, kv = 0.0;
    int ki = 0;
    float psum = 0.0f;
#pragma unroll
    for (int k = 0; k < KSEL; ++k) {
        double bv = -__builtin_inf(); int bi = 0x7fffffff; int bc = 0;
#pragma unroll
        for (int c = 0; c < NCAND; ++c) {
            if (!((selm >> c) & 1u)) {
                if (part[c] > bv || (part[c] == bv && cid[c] < bi)) {
                    bv = part[c]; bi = cid[c]; bc = c;
                }
            }
        }
        if (k == 0) m = bv;
        psum += expf((float)(bv - m));
        if (l == k) { kv = bv; ki = bi; }
        selm |= 1u << bc;
    }

    if (l < KSEL) {
        topv[(size_t)t * KSEL + l] = expf((float)(kv - m)) / psum;
        topi[(size_t)t * KSEL + l] = (float)ki;
    }
}

// ===========================================================================
// Fallback (ws too small): proven round-2 fused fp64 kernel.
// ===========================================================================
#define BM 64
#define BK 32
#define BSTRIDE (BK + 4)
__global__ __launch_bounds__(256) void router_fused(
    const float* __restrict__ x, const float* __restrict__ w,
    float* __restrict__ logits, float* __restrict__ topv, float* __restrict__ topi)
{
    __shared__ float Bs[NEXP][BSTRIDE];
    const int tid = threadIdx.x;
    const int tn = tid & 15, tm = tid >> 4;
    const int row0 = blockIdx.x * BM;
    const int kc = tid & 7, cr = tid >> 3;

    double acc[4][8];
#pragma unroll
    for (int i = 0; i < 4; ++i)
#pragma unroll
        for (int j = 0; j < 8; ++j) acc[i][j] = 0.0;

    const float* xp[4];
#pragma unroll
    for (int i = 0; i < 4; ++i) xp[i] = x + (size_t)(row0 + tm + 16 * i) * HDIM;

    float4 rb[4];
#pragma unroll
    for (int p = 0; p < 4; ++p)
        rb[p] = *reinterpret_cast<const float4*>(&w[(size_t)(cr + 32 * p) * HDIM + kc * 4]);

    for (int k0 = 0; k0 < HDIM; k0 += BK) {
        __syncthreads();
#pragma unroll
        for (int p = 0; p < 4; ++p)
            *reinterpret_cast<float4*>(&Bs[cr + 32 * p][kc * 4]) = rb[p];
        __syncthreads();
        if (k0 + BK < HDIM) {
#pragma unroll
            for (int p = 0; p < 4; ++p)
                rb[p] = *reinterpret_cast<const float4*>(
                    &w[(size_t)(cr + 32 * p) * HDIM + (k0 + BK) + kc * 4]);
        }
#pragma unroll 4
        for (int k4 = 0; k4 < BK; k4 += 4) {
            float4 a4[4], b4[8];
#pragma unroll
            for (int i = 0; i < 4; ++i)
                a4[i] = *reinterpret_cast<const float4*>(&xp[i][k0 + k4]);
#pragma unroll
            for (int j = 0; j < 8; ++j)
                b4[j] = *reinterpret_cast<const float4*>(&Bs[tn + 16 * j][k4]);
#pragma unroll
            for (int kk = 0; kk < 4; ++kk) {
                double bd[8];
#pragma unroll
                for (int j = 0; j < 8; ++j) bd[j] = (double)((const float*)&b4[j])[kk];
#pragma unroll
                for (int i = 0; i < 4; ++i) {
                    const double ad = (double)((const float*)&a4[i])[kk];
#pragma unroll
                    for (int j = 0; j < 8; ++j) acc[i][j] = fma(ad, bd[j], acc[i][j]);
                }
            }
        }
    }
#pragma unroll
    for (int i = 0; i < 4; ++i) {
        float* orow = logits + (size_t)(row0 + tm + 16 * i) * NEXP;
#pragma unroll
        for (int j = 0; j < 8; ++j) orow[tn + 16 * j] = (float)acc[i][j];
    }
    for (int i = 0; i < 4; ++i) {
        const int t = row0 + tm + 16 * i;
        unsigned sel = 0u;
        double m = 0.0, kv = 0.0;
        int ki = 0;
        const double NEGD = -__builtin_inf();
#pragma unroll
        for (int k = 0; k < KSEL; ++k) {
            double lv = NEGD; int le = 0;
#pragma unroll
            for (int j = 0; j < 8; ++j) {
                const double v = (sel >> j) & 1u ? NEGD : acc[i][j];
                if (v > lv) { lv = v; le = tn + 16 * j; }
            }
            double cv = lv; int ce = le;
#pragma unroll
            for (int off = 8; off > 0; off >>= 1) {
                const double ov = __shfl_xor(cv, off, 16);
                const int    oe = __shfl_xor(ce, off, 16);
                if (ov > cv || (ov == cv && oe < ce)) { cv = ov; ce = oe; }
            }
            if (k == 0) m = cv;
            if (tn == k) { kv = cv; ki = ce; }
            if ((ce & 15) == tn) sel |= 1u << (ce >> 4);
        }
        float z = 0.0f;
#pragma unroll
        for (int j = 0; j < 8; ++j) z += expf((float)(acc[i][j] - m));
#pragma unroll
        for (int off = 8; off > 0; off >>= 1) z += __shfl_xor(z, off, 16);
        const float p = (tn < KSEL) ? expf((float)(kv - m)) / z : 0.0f;
        float ps = p;
#pragma unroll
        for (int off = 8; off > 0; off >>= 1) ps += __shfl_xor(ps, off, 16);
        if (tn < KSEL) {
            topv[(size_t)t * KSEL + tn] = p / ps;
            topi[(size_t)t * KSEL + tn] = (float)ki;
        }
    }
}

extern "C" void kernel_launch(void* const* d_in, const int* in_sizes, int n_in,
                              void* d_out, int out_size, void* d_ws, size_t ws_size,
                              hipStream_t stream) {
    const float* x = (const float*)d_in[0];   // [16384, 2048]
    const float* w = (const float*)d_in[1];   // [128, 2048]

    float* out    = (float*)d_out;
    float* logits = out;                                   // 16384*128
    float* topv   = out + (size_t)NTOK * NEXP;             // 16384*8
    float* topi   = topv + (size_t)NTOK * KSEL;            // 16384*8

    // ws layout: whp[512KB] | wlp[512KB] | cand[1MB] | flag[64KB]
    const size_t plane = (size_t)NEXP * HDIM;              // 262144 halfwords
    const size_t need  = plane * 2 * sizeof(_Float16)
                       + (size_t)NTOK * NCAND * sizeof(int)
                       + (size_t)NTOK * sizeof(int);
    if (ws_size >= need) {
        _Float16* whp = (_Float16*)d_ws;
        _Float16* wlp = whp + plane;
        int* cand = (int*)(wlp + plane);
        int* flag = cand + (size_t)NTOK * NCAND;
        w_convert<<<NEXP, 256, 0, stream>>>(w, whp, wlp);
        gemm3_pipe<<<NTOK / 32, 256, 0, stream>>>(x, whp, wlp, logits, topv, topi, cand, flag);
        refine_flagged<<<NTOK / 4, 256, 0, stream>>>(x, w, cand, flag, topv, topi);
    } else {
        router_fused<<<NTOK / BM, 256, 0, stream>>>(x, w, logits, topv, topi);
    }
}